// Round 11
// baseline (643.957 us; speedup 1.0000x reference)
//
#include <hip/hip_runtime.h>
#include <cstdint>
#include <cstddef>

#define NTOK 4096      // H*W
#define HD 64          // head dim
#define CDIM 512       // channels
#define NPAIRS 64      // B * num_heads
#define KV_SPLIT 16    // kv partial splits (256 tokens each)
#define EPS_F 1e-6f
#define EPS_LN 1e-5f
#define ATT_SCALE 0.125
#define PAD 68         // fp32 LDS row pad: 272B rows, 16B-aligned

__device__ __forceinline__ float elu_eps(float y) {
    return (y > 0.f ? y : (__expf(y) - 1.f)) + EPS_F;
}

// 4-wide feature step, operands from LDS (r4-proven shape: safe with live acc).
// TLDS rows are [d][n]-natural; lane reads column fn -> conflict-free.
// W addresses are wave-uniform -> scalar loads (SGPR), no VGPR pressure.
#define FEAT4_LDS(TLDS)                                                           \
    _Pragma("unroll 4")                                                           \
    for (int db = 0; db < 16; ++db) {                                             \
        const float kr0 = TLDS[4 * db + 0][fn];                                   \
        const float kr1 = TLDS[4 * db + 1][fn];                                   \
        const float kr2 = TLDS[4 * db + 2][fn];                                   \
        const float kr3 = TLDS[4 * db + 3][fn];                                   \
        _Pragma("unroll")                                                         \
        for (int j = 0; j < 16; ++j) {                                            \
            const float4 w = *(const float4*)(fm_w + (size_t)(e0f + j) * 64 + 4 * db); \
            a16[j] = fmaf(kr0, w.x, fmaf(kr1, w.y, fmaf(kr2, w.z, fmaf(kr3, w.w, a16[j])))); \
        }                                                                         \
    }

// ---------------------------------------------------------------------------
// K1: fused feature(K)+kv partials, NO atomics (deterministic):
//   kv_part[split][pair][d][e] = sum_{n in split} kf[n][d] v[n][e]
//   ks_part[split][pair][d]    = sum_{n in split} kf[n][d]
// Per 64-token chunk: stage K natural [d][n] (coalesced, no transpose) and
// V transposed [n][e]; feature 4-wide from LDS; broadcast 8x8 GEMM.
// ---------------------------------------------------------------------------
__global__ __launch_bounds__(256, 3) void k_feat_kv(const float* __restrict__ kin,
                                                    const float* __restrict__ vin,
                                                    const float* __restrict__ fm_w,
                                                    const float* __restrict__ fm_b,
                                                    float* __restrict__ kv_part,
                                                    float* __restrict__ ks_part)
{
    __shared__ float kt [64][PAD];   // [d][n] natural K chunk
    __shared__ float vtT[64][PAD];   // [n][e] transposed V chunk
    __shared__ float kf [64][PAD];   // [n][d_f] feature out; reused as Red

    const int tid  = threadIdx.x;
    const int lane = tid & 63;
    const int wv   = tid >> 6;

    const int pair  = blockIdx.x >> 4;
    const int split = blockIdx.x & (KV_SPLIT - 1);
    const int bb = pair >> 3, hh = pair & 7;
    const float* kb = kin + (size_t)(bb * CDIM + hh * HD) * NTOK;
    const float* vb = vin + (size_t)(bb * CDIM + hh * HD) * NTOK;

    const int fn  = lane;              // feature token (within chunk)
    const int e0f = wv * 16;           // feature d_f-range (wave-owned)
    const int dq  = (tid >> 4) * 4;    // staging row quad
    const int nq  = (tid & 15) * 4;    // staging col quad
    const int d0  = (lane >> 3) * 8;   // GEMM tile rows
    const int e0  = (lane & 7) * 8;    // GEMM tile cols

    float ksp[16];
    #pragma unroll
    for (int j = 0; j < 16; ++j) ksp[j] = 0.f;
    float acc[8][8];
    #pragma unroll
    for (int i = 0; i < 8; ++i)
        #pragma unroll
        for (int j = 0; j < 8; ++j) acc[i][j] = 0.f;

    #pragma unroll 1
    for (int c = 0; c < 4; ++c) {
        const int n0 = split * 256 + c * 64;
        __syncthreads();   // previous chunk's GEMM reads done

        // ---- stage K natural [d][n]: coalesced float4 both sides ----
        #pragma unroll
        for (int r = 0; r < 4; ++r)
            *(float4*)&kt[dq + r][nq] =
                *(const float4*)(kb + (size_t)(dq + r) * NTOK + n0 + nq);
        // ---- stage V transposed [n][e]: 4x4 register transpose ----
        {
            float4 x0 = *(const float4*)(vb + (size_t)(dq + 0) * NTOK + n0 + nq);
            float4 x1 = *(const float4*)(vb + (size_t)(dq + 1) * NTOK + n0 + nq);
            float4 x2 = *(const float4*)(vb + (size_t)(dq + 2) * NTOK + n0 + nq);
            float4 x3 = *(const float4*)(vb + (size_t)(dq + 3) * NTOK + n0 + nq);
            *(float4*)&vtT[nq + 0][dq] = make_float4(x0.x, x1.x, x2.x, x3.x);
            *(float4*)&vtT[nq + 1][dq] = make_float4(x0.y, x1.y, x2.y, x3.y);
            *(float4*)&vtT[nq + 2][dq] = make_float4(x0.z, x1.z, x2.z, x3.z);
            *(float4*)&vtT[nq + 3][dq] = make_float4(x0.w, x1.w, x2.w, x3.w);
        }
        __syncthreads();

        // ---- feature map for token fn (operands from LDS) ----
        {
            float a16[16];
            #pragma unroll
            for (int j = 0; j < 16; ++j) a16[j] = fm_b[e0f + j];
            FEAT4_LDS(kt)
            #pragma unroll
            for (int j = 0; j < 16; ++j) {
                a16[j] = elu_eps(a16[j]);
                ksp[j] += a16[j];
            }
            #pragma unroll
            for (int i = 0; i < 4; ++i)
                *(float4*)&kf[fn][e0f + 4 * i] =
                    make_float4(a16[4 * i], a16[4 * i + 1], a16[4 * i + 2], a16[4 * i + 3]);
        }
        __syncthreads();

        // ---- broadcast 8x8 GEMM: wave wv owns tokens [16wv, 16wv+16) ----
        #pragma unroll 4
        for (int tt = 0; tt < 16; ++tt) {
            const int n = 16 * wv + tt;   // wave-uniform -> broadcast LDS reads
            const float4 a0_ = *(const float4*)&kf[n][d0];
            const float4 a1_ = *(const float4*)&kf[n][d0 + 4];
            const float4 b0_ = *(const float4*)&vtT[n][e0];
            const float4 b1_ = *(const float4*)&vtT[n][e0 + 4];
            const float av[8] = {a0_.x, a0_.y, a0_.z, a0_.w, a1_.x, a1_.y, a1_.z, a1_.w};
            const float bv[8] = {b0_.x, b0_.y, b0_.z, b0_.w, b1_.x, b1_.y, b1_.z, b1_.w};
            #pragma unroll
            for (int i = 0; i < 8; ++i)
                #pragma unroll
                for (int j = 0; j < 8; ++j)
                    acc[i][j] = fmaf(av[i], bv[j], acc[i][j]);
        }
    }

    // ---- ksum: shuffle-reduce over lanes; lane 0 stores (no atomic) ----
    #pragma unroll
    for (int j = 0; j < 16; ++j) {
        float v = ksp[j];
        v += __shfl_xor(v, 1, 64);
        v += __shfl_xor(v, 2, 64);
        v += __shfl_xor(v, 4, 64);
        v += __shfl_xor(v, 8, 64);
        v += __shfl_xor(v, 16, 64);
        v += __shfl_xor(v, 32, 64);
        if (lane == 0)
            ks_part[((size_t)split * NPAIRS + pair) * HD + e0f + j] = v;
    }

    // ---- cross-wave reduce (reuse kf as Red), store partial ----
    __syncthreads();
    for (int w = 0; w < 4; ++w) {
        if (wv == w) {
            #pragma unroll
            for (int i = 0; i < 8; ++i) {
                if (w == 0) {
                    *(float4*)&kf[d0 + i][e0]     = make_float4(acc[i][0], acc[i][1], acc[i][2], acc[i][3]);
                    *(float4*)&kf[d0 + i][e0 + 4] = make_float4(acc[i][4], acc[i][5], acc[i][6], acc[i][7]);
                } else {
                    float4 r0 = *(const float4*)&kf[d0 + i][e0];
                    float4 r1 = *(const float4*)&kf[d0 + i][e0 + 4];
                    r0.x += acc[i][0]; r0.y += acc[i][1]; r0.z += acc[i][2]; r0.w += acc[i][3];
                    r1.x += acc[i][4]; r1.y += acc[i][5]; r1.z += acc[i][6]; r1.w += acc[i][7];
                    *(float4*)&kf[d0 + i][e0]     = r0;
                    *(float4*)&kf[d0 + i][e0 + 4] = r1;
                }
            }
        }
        __syncthreads();
    }
    {
        float* kvp = kv_part + ((size_t)split * NPAIRS + pair) * (HD * HD);
        const int r0 = (tid >> 4) * 4;
        const int c0 = (tid & 15) * 4;
        #pragma unroll
        for (int i = 0; i < 4; ++i)
            *(float4*)(kvp + (size_t)(r0 + i) * HD + c0) = *(const float4*)&kf[r0 + i][c0];
    }
}

// ---------------------------------------------------------------------------
// K1c: deterministic fixed-order fp64 reduce of the 16 split partials.
// ---------------------------------------------------------------------------
__global__ __launch_bounds__(256) void k_reduce(const float* __restrict__ kv_part,
                                                const float* __restrict__ ks_part,
                                                float* __restrict__ kv_g,
                                                float* __restrict__ ksum_g)
{
    const int pair = blockIdx.x >> 2;
    const int qtr  = blockIdx.x & 3;
    const int tid  = threadIdx.x;

    #pragma unroll
    for (int i = 0; i < 4; ++i) {
        const int idx = qtr * 1024 + i * 256 + tid;
        double s = 0.0;
        for (int sp = 0; sp < KV_SPLIT; ++sp)
            s += (double)kv_part[((size_t)sp * NPAIRS + pair) * (HD * HD) + idx];
        kv_g[(size_t)pair * (HD * HD) + idx] = (float)(s * ATT_SCALE);
    }
    if (qtr == 0 && tid < HD) {
        double s = 0.0;
        for (int sp = 0; sp < KV_SPLIT; ++sp)
            s += (double)ks_part[((size_t)sp * NPAIRS + pair) * HD + tid];
        ksum_g[(size_t)pair * HD + tid] = (float)s;
    }
}

// ---------------------------------------------------------------------------
// K2: out[n][e] = (qf[n]·kv[:,e]) / (qf[n]·ksum + eps), fp32.
// r10 structure + Q staged through LDS (kills the global-column-read stalls).
// ---------------------------------------------------------------------------
__global__ __launch_bounds__(256, 3) void k_qout(const float* __restrict__ qin,
                                                 const float* __restrict__ fm_w,
                                                 const float* __restrict__ fm_b,
                                                 const float* __restrict__ kv_g,
                                                 const float* __restrict__ ksum_g,
                                                 float* __restrict__ outp)
{
    __shared__ float kvs[64][PAD];   // [d][e]
    __shared__ float qt [64][PAD];   // [d][n] natural Q chunk
    __shared__ float qfT[64][PAD];   // [d_f][n]; reused as RedT after out phase
    __shared__ float nred[4][64];
    __shared__ float norm_lds[64];

    const int tid  = threadIdx.x;
    const int lane = tid & 63;
    const int wv   = tid >> 6;

    const int pair  = blockIdx.x >> 6;
    const int chunk = blockIdx.x & 63;
    const int n0    = chunk * 64;
    const int bb = pair >> 3, hh = pair & 7;
    const float* qb = qin + (size_t)(bb * CDIM + hh * HD) * NTOK;

    const int dq = (tid >> 4) * 4;
    const int nq = (tid & 15) * 4;

    // ---- stage kv tile + Q chunk (natural [d][n], coalesced) ----
    {
        const float* kvg = kv_g + (size_t)pair * (HD * HD);
        const int d  = tid >> 2;
        const int eb = (tid & 3) * 16;
        #pragma unroll
        for (int i = 0; i < 4; ++i)
            *(float4*)&kvs[d][eb + 4 * i] = *(const float4*)(kvg + (size_t)d * 64 + eb + 4 * i);
        #pragma unroll
        for (int r = 0; r < 4; ++r)
            *(float4*)&qt[dq + r][nq] =
                *(const float4*)(qb + (size_t)(dq + r) * NTOK + n0 + nq);
    }

    const int fn  = lane;
    const int e0f = wv * 16;
    float ksr[16];
    #pragma unroll
    for (int j = 0; j < 16; ++j) ksr[j] = ksum_g[(size_t)pair * HD + e0f + j];
    __syncthreads();

    // ---- feature map (Q from LDS) -> qfT + normalizer partial ----
    {
        float a16[16];
        #pragma unroll
        for (int j = 0; j < 16; ++j) a16[j] = fm_b[e0f + j];
        FEAT4_LDS(qt)
        float np = 0.f;
        #pragma unroll
        for (int j = 0; j < 16; ++j) {
            const float v = elu_eps(a16[j]);
            np = fmaf(v, ksr[j], np);
            qfT[e0f + j][fn] = v;
        }
        nred[wv][fn] = np;
    }
    __syncthreads();
    if (tid < 64)
        norm_lds[tid] = nred[0][tid] + nred[1][tid] + nred[2][tid] + nred[3][tid] + EPS_F;
    __syncthreads();

    // ---- out GEMM (transposed acc): wave wv owns d in [16wv, 16wv+16) ----
    const int ea0 = (lane >> 3) * 8;
    const int na0 = (lane & 7) * 8;
    float acc[8][8];
    #pragma unroll
    for (int i = 0; i < 8; ++i)
        #pragma unroll
        for (int j = 0; j < 8; ++j) acc[i][j] = 0.f;
    #pragma unroll
    for (int dd = 0; dd < 16; ++dd) {
        const int d = 16 * wv + dd;   // wave-uniform
        const float4 a0_ = *(const float4*)&kvs[d][ea0];
        const float4 a1_ = *(const float4*)&kvs[d][ea0 + 4];
        const float4 b0_ = *(const float4*)&qfT[d][na0];
        const float4 b1_ = *(const float4*)&qfT[d][na0 + 4];
        const float av[8] = {a0_.x, a0_.y, a0_.z, a0_.w, a1_.x, a1_.y, a1_.z, a1_.w};
        const float bv[8] = {b0_.x, b0_.y, b0_.z, b0_.w, b1_.x, b1_.y, b1_.z, b1_.w};
        #pragma unroll
        for (int i = 0; i < 8; ++i)
            #pragma unroll
            for (int j = 0; j < 8; ++j)
                acc[i][j] = fmaf(av[i], bv[j], acc[i][j]);
    }
    __syncthreads();   // all qfT reads done; safe to overwrite as RedT

    for (int w = 0; w < 4; ++w) {
        if (wv == w) {
            #pragma unroll
            for (int i = 0; i < 8; ++i) {
                if (w == 0) {
                    *(float4*)&qfT[ea0 + i][na0]     = make_float4(acc[i][0], acc[i][1], acc[i][2], acc[i][3]);
                    *(float4*)&qfT[ea0 + i][na0 + 4] = make_float4(acc[i][4], acc[i][5], acc[i][6], acc[i][7]);
                } else {
                    float4 r0 = *(const float4*)&qfT[ea0 + i][na0];
                    float4 r1 = *(const float4*)&qfT[ea0 + i][na0 + 4];
                    r0.x += acc[i][0]; r0.y += acc[i][1]; r0.z += acc[i][2]; r0.w += acc[i][3];
                    r1.x += acc[i][4]; r1.y += acc[i][5]; r1.z += acc[i][6]; r1.w += acc[i][7];
                    *(float4*)&qfT[ea0 + i][na0]     = r0;
                    *(float4*)&qfT[ea0 + i][na0 + 4] = r1;
                }
            }
        }
        __syncthreads();
    }

    // ---- epilogue: divide by normalizer, coalesced store ----
    {
        const int er0 = (tid >> 4) * 4;   // e rows
        const int nc0 = (tid & 15) * 4;   // n cols
        float rn[4];
        #pragma unroll
        for (int j = 0; j < 4; ++j) rn[j] = 1.f / norm_lds[nc0 + j];
        float* ob = outp + (size_t)(bb * CDIM + hh * HD) * NTOK + n0;
        #pragma unroll
        for (int i = 0; i < 4; ++i) {
            float4 vv = *(const float4*)&qfT[er0 + i][nc0];
            vv.x *= rn[0]; vv.y *= rn[1]; vv.z *= rn[2]; vv.w *= rn[3];
            *(float4*)(ob + (size_t)(er0 + i) * NTOK + nc0) = vv;
        }
    }
}

// ---------------------------------------------------------------------------
// K3: in-place LayerNorm over C, 16 tokens/block, two-pass variance
// ---------------------------------------------------------------------------
__global__ __launch_bounds__(256) void k_layernorm(float* __restrict__ io,
                                                   const float* __restrict__ ln_w,
                                                   const float* __restrict__ ln_b)
{
    __shared__ float xs[512][17];
    __shared__ float mu_s[16];
    __shared__ float rs_s[16];

    const int tid = threadIdx.x;
    const int bb = blockIdx.x >> 8;
    const int chunk = blockIdx.x & 255;
    const int n0 = chunk * 16;
    float* base = io + (size_t)bb * CDIM * NTOK + n0;

    #pragma unroll
    for (int i = 0; i < 8; ++i) {
        const int idx = tid + i * 256;
        const int c = idx >> 2;
        const int f4 = (idx & 3) * 4;
        const float4 vx = *(const float4*)(base + (size_t)c * NTOK + f4);
        xs[c][f4 + 0] = vx.x; xs[c][f4 + 1] = vx.y;
        xs[c][f4 + 2] = vx.z; xs[c][f4 + 3] = vx.w;
    }
    __syncthreads();

    const int n = tid >> 4;
    const int p = tid & 15;
    float s = 0.f;
    #pragma unroll 8
    for (int ci = 0; ci < 32; ++ci) {
        const int c = p * 32 + ((ci + 2 * p) & 31);
        s += xs[c][n];
    }
    s += __shfl_xor(s, 1, 64);
    s += __shfl_xor(s, 2, 64);
    s += __shfl_xor(s, 4, 64);
    s += __shfl_xor(s, 8, 64);
    if (p == 0) mu_s[n] = s * (1.f / 512.f);
    __syncthreads();
    const float mu = mu_s[n];
    float s2 = 0.f;
    #pragma unroll 8
    for (int ci = 0; ci < 32; ++ci) {
        const int c = p * 32 + ((ci + 2 * p) & 31);
        const float x = xs[c][n] - mu;
        s2 = fmaf(x, x, s2);
    }
    s2 += __shfl_xor(s2, 1, 64);
    s2 += __shfl_xor(s2, 2, 64);
    s2 += __shfl_xor(s2, 4, 64);
    s2 += __shfl_xor(s2, 8, 64);
    if (p == 0) rs_s[n] = rsqrtf(s2 * (1.f / 512.f) + EPS_LN);
    __syncthreads();

    #pragma unroll
    for (int i = 0; i < 8; ++i) {
        const int idx = tid + i * 256;
        const int c = idx >> 2;
        const int f4 = (idx & 3) * 4;
        const float w = ln_w[c];
        const float b2 = ln_b[c];
        float4 ov;
        ov.x = (xs[c][f4 + 0] - mu_s[f4 + 0]) * rs_s[f4 + 0] * w + b2;
        ov.y = (xs[c][f4 + 1] - mu_s[f4 + 1]) * rs_s[f4 + 1] * w + b2;
        ov.z = (xs[c][f4 + 2] - mu_s[f4 + 2]) * rs_s[f4 + 2] * w + b2;
        ov.w = (xs[c][f4 + 3] - mu_s[f4 + 3]) * rs_s[f4 + 3] * w + b2;
        *(float4*)(base + (size_t)c * NTOK + f4) = ov;
    }
}

// ---------------------------------------------------------------------------
extern "C" void kernel_launch(void* const* d_in, const int* in_sizes, int n_in,
                              void* d_out, int out_size, void* d_ws, size_t ws_size,
                              hipStream_t stream) {
    (void)in_sizes; (void)n_in; (void)out_size; (void)ws_size;
    const float* q    = (const float*)d_in[0];
    const float* k    = (const float*)d_in[1];
    const float* v    = (const float*)d_in[2];
    const float* fm_w = (const float*)d_in[3];
    const float* fm_b = (const float*)d_in[4];
    const float* ln_w = (const float*)d_in[5];
    const float* ln_b = (const float*)d_in[6];
    float* out = (float*)d_out;

    // ws layout (all regions fully written before read; no memset needed):
    float* kv_part = (float*)d_ws;                                   // 16*64*4096 floats
    float* ks_part = kv_part + (size_t)KV_SPLIT * NPAIRS * HD * HD;  // 16*64*64
    float* kv_g    = ks_part + (size_t)KV_SPLIT * NPAIRS * HD;       // 64*4096
    float* ksum_g  = kv_g    + (size_t)NPAIRS * HD * HD;             // 64*64

    k_feat_kv<<<NPAIRS * KV_SPLIT, 256, 0, stream>>>(k, v, fm_w, fm_b, kv_part, ks_part);
    k_reduce<<<NPAIRS * 4, 256, 0, stream>>>(kv_part, ks_part, kv_g, ksum_g);
    k_qout<<<NPAIRS * (NTOK / 64), 256, 0, stream>>>(q, fm_w, fm_b, kv_g, ksum_g, out);
    k_layernorm<<<8 * (NTOK / 16), 256, 0, stream>>>(out, ln_w, ln_b);
}

// Round 12
// 601.621 us; speedup vs baseline: 1.0704x; 1.0704x over previous
//
#include <hip/hip_runtime.h>
#include <cstdint>
#include <cstddef>

#define NTOK 4096      // H*W
#define HD 64          // head dim
#define CDIM 512       // channels
#define NPAIRS 64      // B * num_heads
#define KV_SPLIT 16    // kv partial splits (256 tokens each)
#define EPS_F 1e-6f
#define EPS_LN 1e-5f
#define ATT_SCALE 0.125
#define PAD 68         // fp32 LDS row pad: 272B rows, 16B-aligned
#define FPAD 72        // k_feat_k output LDS pad

__device__ __forceinline__ float elu_eps(float y) {
    return (y > 0.f ? y : (__expf(y) - 1.f)) + EPS_F;
}

// 4-wide feature step, operands from LDS (r4-proven). TLDS rows are
// [d][n]-natural; lane reads column fn (2-way bank alias = free).
// W addresses wave-uniform -> scalar loads.
#define FEAT4_LDS(TLDS)                                                           \
    _Pragma("unroll 4")                                                           \
    for (int db = 0; db < 16; ++db) {                                             \
        const float kr0 = TLDS[4 * db + 0][fn];                                   \
        const float kr1 = TLDS[4 * db + 1][fn];                                   \
        const float kr2 = TLDS[4 * db + 2][fn];                                   \
        const float kr3 = TLDS[4 * db + 3][fn];                                   \
        _Pragma("unroll")                                                         \
        for (int j = 0; j < 16; ++j) {                                            \
            const float4 w = *(const float4*)(fm_w + (size_t)(e0f + j) * 64 + 4 * db); \
            a16[j] = fmaf(kr0, w.x, fmaf(kr1, w.y, fmaf(kr2, w.z, fmaf(kr3, w.w, a16[j])))); \
        }                                                                         \
    }

// ---------------------------------------------------------------------------
// K1a: feature map over K. K staged to LDS (coalesced, natural [d][n]);
// feature 4-wide from LDS; output via LDS transpose + coalesced full-line
// stores (r10-proven). No accumulator -> no spill surface.
//   kf_ws[pair][d][n];  ks_part[chunk][pair][d]
// ---------------------------------------------------------------------------
__global__ __launch_bounds__(256, 4) void k_feat_k(const float* __restrict__ kin,
                                                   const float* __restrict__ fm_w,
                                                   const float* __restrict__ fm_b,
                                                   float* __restrict__ kf_ws,
                                                   float* __restrict__ ks_part)
{
    __shared__ float kt [64][PAD];    // [d][n] natural K chunk
    __shared__ float kfT[64][FPAD];   // [d_f][n]

    const int tid  = threadIdx.x;
    const int lane = tid & 63;
    const int wv   = tid >> 6;

    const int pair  = blockIdx.x >> 6;
    const int chunk = blockIdx.x & 63;
    const int n0    = chunk * 64;
    const int bb = pair >> 3, hh = pair & 7;
    const float* kb = kin + (size_t)(bb * CDIM + hh * HD) * NTOK;

    const int dq = (tid >> 4) * 4;    // staging row quad
    const int nq = (tid & 15) * 4;    // staging col quad

    // ---- stage K natural [d][n]: coalesced float4 both sides ----
    #pragma unroll
    for (int r = 0; r < 4; ++r)
        *(float4*)&kt[dq + r][nq] =
            *(const float4*)(kb + (size_t)(dq + r) * NTOK + n0 + nq);
    __syncthreads();

    const int fn  = lane;
    const int e0f = wv * 16;

    float a16[16];
    #pragma unroll
    for (int j = 0; j < 16; ++j) a16[j] = fm_b[e0f + j];
    FEAT4_LDS(kt)

    #pragma unroll
    for (int j = 0; j < 16; ++j) {
        a16[j] = elu_eps(a16[j]);
        kfT[e0f + j][fn] = a16[j];    // 64 lanes, consecutive cols: conflict-free
    }

    // ksum chunk-partials (shuffle reduce; deterministic, no atomics)
    #pragma unroll
    for (int j = 0; j < 16; ++j) {
        float v = a16[j];
        v += __shfl_xor(v, 1, 64);
        v += __shfl_xor(v, 2, 64);
        v += __shfl_xor(v, 4, 64);
        v += __shfl_xor(v, 8, 64);
        v += __shfl_xor(v, 16, 64);
        v += __shfl_xor(v, 32, 64);
        if (lane == 0)
            ks_part[((size_t)chunk * NPAIRS + pair) * HD + e0f + j] = v;
    }

    __syncthreads();

    // coalesced write-out: 16-lane groups write contiguous 256B runs per row
    float* kfb = kf_ws + (size_t)pair * HD * NTOK;
    const int dr = tid >> 4;
    const int nc = (tid & 15) * 4;
    #pragma unroll
    for (int i = 0; i < 4; ++i) {
        const int d = dr + 16 * i;
        *(float4*)(kfb + (size_t)d * NTOK + n0 + nc) = *(const float4*)&kfT[d][nc];
    }
}

// ---------------------------------------------------------------------------
// K1b: pure GEMM  kv_part[split][pair][d][e] (verbatim r9/r10 — no spills)
// ---------------------------------------------------------------------------
__global__ __launch_bounds__(256, 3) void k_kv(const float* __restrict__ vin,
                                               const float* __restrict__ kf_ws,
                                               float* __restrict__ kv_part)
{
    __shared__ float kf_l[64][PAD];   // [n][d]
    __shared__ float vtT[64][PAD];    // [n][e]

    const int tid  = threadIdx.x;
    const int lane = tid & 63;
    const int wv   = tid >> 6;

    const int pair  = blockIdx.x >> 4;
    const int split = blockIdx.x & (KV_SPLIT - 1);
    const int bb = pair >> 3, hh = pair & 7;
    const float* vb  = vin + (size_t)(bb * CDIM + hh * HD) * NTOK;
    const float* kfb = kf_ws + (size_t)pair * HD * NTOK;

    const int dq = (tid >> 4) * 4;
    const int nq = (tid & 15) * 4;
    const int d0 = (lane >> 3) * 8;
    const int e0 = (lane & 7) * 8;

    float acc[8][8];
    #pragma unroll
    for (int i = 0; i < 8; ++i)
        #pragma unroll
        for (int j = 0; j < 8; ++j) acc[i][j] = 0.f;

    #pragma unroll 1
    for (int c = 0; c < 4; ++c) {
        const int n0 = split * 256 + c * 64;
        __syncthreads();

        {
            float4 x0 = *(const float4*)(kfb + (size_t)(dq + 0) * NTOK + n0 + nq);
            float4 x1 = *(const float4*)(kfb + (size_t)(dq + 1) * NTOK + n0 + nq);
            float4 x2 = *(const float4*)(kfb + (size_t)(dq + 2) * NTOK + n0 + nq);
            float4 x3 = *(const float4*)(kfb + (size_t)(dq + 3) * NTOK + n0 + nq);
            *(float4*)&kf_l[nq + 0][dq] = make_float4(x0.x, x1.x, x2.x, x3.x);
            *(float4*)&kf_l[nq + 1][dq] = make_float4(x0.y, x1.y, x2.y, x3.y);
            *(float4*)&kf_l[nq + 2][dq] = make_float4(x0.z, x1.z, x2.z, x3.z);
            *(float4*)&kf_l[nq + 3][dq] = make_float4(x0.w, x1.w, x2.w, x3.w);
        }
        {
            float4 x0 = *(const float4*)(vb + (size_t)(dq + 0) * NTOK + n0 + nq);
            float4 x1 = *(const float4*)(vb + (size_t)(dq + 1) * NTOK + n0 + nq);
            float4 x2 = *(const float4*)(vb + (size_t)(dq + 2) * NTOK + n0 + nq);
            float4 x3 = *(const float4*)(vb + (size_t)(dq + 3) * NTOK + n0 + nq);
            *(float4*)&vtT[nq + 0][dq] = make_float4(x0.x, x1.x, x2.x, x3.x);
            *(float4*)&vtT[nq + 1][dq] = make_float4(x0.y, x1.y, x2.y, x3.y);
            *(float4*)&vtT[nq + 2][dq] = make_float4(x0.z, x1.z, x2.z, x3.z);
            *(float4*)&vtT[nq + 3][dq] = make_float4(x0.w, x1.w, x2.w, x3.w);
        }
        __syncthreads();

        #pragma unroll 4
        for (int tt = 0; tt < 16; ++tt) {
            const int n = 16 * wv + tt;
            const float4 a0_ = *(const float4*)&kf_l[n][d0];
            const float4 a1_ = *(const float4*)&kf_l[n][d0 + 4];
            const float4 b0_ = *(const float4*)&vtT[n][e0];
            const float4 b1_ = *(const float4*)&vtT[n][e0 + 4];
            const float av[8] = {a0_.x, a0_.y, a0_.z, a0_.w, a1_.x, a1_.y, a1_.z, a1_.w};
            const float bv[8] = {b0_.x, b0_.y, b0_.z, b0_.w, b1_.x, b1_.y, b1_.z, b1_.w};
            #pragma unroll
            for (int i = 0; i < 8; ++i)
                #pragma unroll
                for (int j = 0; j < 8; ++j)
                    acc[i][j] = fmaf(av[i], bv[j], acc[i][j]);
        }
    }

    __syncthreads();
    for (int w = 0; w < 4; ++w) {
        if (wv == w) {
            #pragma unroll
            for (int i = 0; i < 8; ++i) {
                if (w == 0) {
                    *(float4*)&kf_l[d0 + i][e0]     = make_float4(acc[i][0], acc[i][1], acc[i][2], acc[i][3]);
                    *(float4*)&kf_l[d0 + i][e0 + 4] = make_float4(acc[i][4], acc[i][5], acc[i][6], acc[i][7]);
                } else {
                    float4 r0 = *(const float4*)&kf_l[d0 + i][e0];
                    float4 r1 = *(const float4*)&kf_l[d0 + i][e0 + 4];
                    r0.x += acc[i][0]; r0.y += acc[i][1]; r0.z += acc[i][2]; r0.w += acc[i][3];
                    r1.x += acc[i][4]; r1.y += acc[i][5]; r1.z += acc[i][6]; r1.w += acc[i][7];
                    *(float4*)&kf_l[d0 + i][e0]     = r0;
                    *(float4*)&kf_l[d0 + i][e0 + 4] = r1;
                }
            }
        }
        __syncthreads();
    }
    {
        float* kvp = kv_part + ((size_t)split * NPAIRS + pair) * (HD * HD);
        const int r0 = (tid >> 4) * 4;
        const int c0 = (tid & 15) * 4;
        #pragma unroll
        for (int i = 0; i < 4; ++i)
            *(float4*)(kvp + (size_t)(r0 + i) * HD + c0) = *(const float4*)&kf_l[r0 + i][c0];
    }
}

// ---------------------------------------------------------------------------
// K1c: deterministic fixed-order fp64 reduce of partials (verbatim r10).
// ---------------------------------------------------------------------------
__global__ __launch_bounds__(256) void k_reduce(const float* __restrict__ kv_part,
                                                const float* __restrict__ ks_part,
                                                float* __restrict__ kv_g,
                                                float* __restrict__ ksum_g)
{
    const int pair = blockIdx.x >> 2;
    const int qtr  = blockIdx.x & 3;
    const int tid  = threadIdx.x;

    #pragma unroll
    for (int i = 0; i < 4; ++i) {
        const int idx = qtr * 1024 + i * 256 + tid;
        double s = 0.0;
        for (int sp = 0; sp < KV_SPLIT; ++sp)
            s += (double)kv_part[((size_t)sp * NPAIRS + pair) * (HD * HD) + idx];
        kv_g[(size_t)pair * (HD * HD) + idx] = (float)(s * ATT_SCALE);
    }
    if (qtr == 0 && tid < HD) {
        double s = 0.0;
        for (int c = 0; c < 64; ++c)
            s += (double)ks_part[((size_t)c * NPAIRS + pair) * HD + tid];
        ksum_g[(size_t)pair * HD + tid] = (float)s;
    }
}

// ---------------------------------------------------------------------------
// K2: out[n][e] = (qf[n]·kv[:,e]) / (qf[n]·ksum + eps), fp32.
// r10 kernel + Q staged via LDS with BUFFER REUSE: Q lives in bufA only until
// the feature phase ends; kv tile then overwrites bufA. LDS stays ~36KB so
// launch_bounds(256,3) remains satisfiable (r11 lesson).
// ---------------------------------------------------------------------------
__global__ __launch_bounds__(256, 3) void k_qout(const float* __restrict__ qin,
                                                 const float* __restrict__ fm_w,
                                                 const float* __restrict__ fm_b,
                                                 const float* __restrict__ kv_g,
                                                 const float* __restrict__ ksum_g,
                                                 float* __restrict__ outp)
{
    __shared__ float bufA[64][PAD];   // Q chunk [d][n], then kv tile [d][e]
    __shared__ float bufB[64][PAD];   // qfT [d_f][n], then RedT
    __shared__ float nred[4][64];
    __shared__ float norm_lds[64];

    const int tid  = threadIdx.x;
    const int lane = tid & 63;
    const int wv   = tid >> 6;

    const int pair  = blockIdx.x >> 6;
    const int chunk = blockIdx.x & 63;
    const int n0    = chunk * 64;
    const int bb = pair >> 3, hh = pair & 7;
    const float* qb = qin + (size_t)(bb * CDIM + hh * HD) * NTOK;

    const int dq = (tid >> 4) * 4;
    const int nq = (tid & 15) * 4;

    // ---- stage Q natural [d][n] into bufA ----
    #pragma unroll
    for (int r = 0; r < 4; ++r)
        *(float4*)&bufA[dq + r][nq] =
            *(const float4*)(qb + (size_t)(dq + r) * NTOK + n0 + nq);

    const int fn  = lane;
    const int e0f = wv * 16;
    float ksr[16];
    #pragma unroll
    for (int j = 0; j < 16; ++j) ksr[j] = ksum_g[(size_t)pair * HD + e0f + j];
    __syncthreads();

    // ---- feature map (Q from LDS) -> bufB(qfT) + normalizer partial ----
    {
        float a16[16];
        #pragma unroll
        for (int j = 0; j < 16; ++j) a16[j] = fm_b[e0f + j];
        FEAT4_LDS(bufA)
        float np = 0.f;
        #pragma unroll
        for (int j = 0; j < 16; ++j) {
            const float v = elu_eps(a16[j]);
            np = fmaf(v, ksr[j], np);
            bufB[e0f + j][fn] = v;
        }
        nred[wv][fn] = np;
    }
    __syncthreads();   // feature reads of bufA done -> safe to overwrite

    // ---- stage kv tile into bufA (Q is dead) + norm reduce ----
    {
        const float* kvg = kv_g + (size_t)pair * (HD * HD);
        const int d  = tid >> 2;
        const int eb = (tid & 3) * 16;
        #pragma unroll
        for (int i = 0; i < 4; ++i)
            *(float4*)&bufA[d][eb + 4 * i] = *(const float4*)(kvg + (size_t)d * 64 + eb + 4 * i);
    }
    if (tid < 64)
        norm_lds[tid] = nred[0][tid] + nred[1][tid] + nred[2][tid] + nred[3][tid] + EPS_F;
    __syncthreads();

    // ---- out GEMM (transposed acc): wave wv owns d in [16wv, 16wv+16) ----
    const int ea0 = (lane >> 3) * 8;
    const int na0 = (lane & 7) * 8;
    float acc[8][8];
    #pragma unroll
    for (int i = 0; i < 8; ++i)
        #pragma unroll
        for (int j = 0; j < 8; ++j) acc[i][j] = 0.f;
    #pragma unroll
    for (int dd = 0; dd < 16; ++dd) {
        const int d = 16 * wv + dd;   // wave-uniform
        const float4 a0_ = *(const float4*)&bufA[d][ea0];
        const float4 a1_ = *(const float4*)&bufA[d][ea0 + 4];
        const float4 b0_ = *(const float4*)&bufB[d][na0];
        const float4 b1_ = *(const float4*)&bufB[d][na0 + 4];
        const float av[8] = {a0_.x, a0_.y, a0_.z, a0_.w, a1_.x, a1_.y, a1_.z, a1_.w};
        const float bv[8] = {b0_.x, b0_.y, b0_.z, b0_.w, b1_.x, b1_.y, b1_.z, b1_.w};
        #pragma unroll
        for (int i = 0; i < 8; ++i)
            #pragma unroll
            for (int j = 0; j < 8; ++j)
                acc[i][j] = fmaf(av[i], bv[j], acc[i][j]);
    }
    __syncthreads();   // all bufB reads done; safe to overwrite as RedT

    for (int w = 0; w < 4; ++w) {
        if (wv == w) {
            #pragma unroll
            for (int i = 0; i < 8; ++i) {
                if (w == 0) {
                    *(float4*)&bufB[ea0 + i][na0]     = make_float4(acc[i][0], acc[i][1], acc[i][2], acc[i][3]);
                    *(float4*)&bufB[ea0 + i][na0 + 4] = make_float4(acc[i][4], acc[i][5], acc[i][6], acc[i][7]);
                } else {
                    float4 r0 = *(const float4*)&bufB[ea0 + i][na0];
                    float4 r1 = *(const float4*)&bufB[ea0 + i][na0 + 4];
                    r0.x += acc[i][0]; r0.y += acc[i][1]; r0.z += acc[i][2]; r0.w += acc[i][3];
                    r1.x += acc[i][4]; r1.y += acc[i][5]; r1.z += acc[i][6]; r1.w += acc[i][7];
                    *(float4*)&bufB[ea0 + i][na0]     = r0;
                    *(float4*)&bufB[ea0 + i][na0 + 4] = r1;
                }
            }
        }
        __syncthreads();
    }

    // ---- epilogue: divide by normalizer, coalesced store ----
    {
        const int er0 = (tid >> 4) * 4;
        const int nc0 = (tid & 15) * 4;
        float rn[4];
        #pragma unroll
        for (int j = 0; j < 4; ++j) rn[j] = 1.f / norm_lds[nc0 + j];
        float* ob = outp + (size_t)(bb * CDIM + hh * HD) * NTOK + n0;
        #pragma unroll
        for (int i = 0; i < 4; ++i) {
            float4 vv = *(const float4*)&bufB[er0 + i][nc0];
            vv.x *= rn[0]; vv.y *= rn[1]; vv.z *= rn[2]; vv.w *= rn[3];
            *(float4*)(ob + (size_t)(er0 + i) * NTOK + nc0) = vv;
        }
    }
}

// ---------------------------------------------------------------------------
// K3: in-place LayerNorm over C, 16 tokens/block, two-pass variance (r10)
// ---------------------------------------------------------------------------
__global__ __launch_bounds__(256) void k_layernorm(float* __restrict__ io,
                                                   const float* __restrict__ ln_w,
                                                   const float* __restrict__ ln_b)
{
    __shared__ float xs[512][17];
    __shared__ float mu_s[16];
    __shared__ float rs_s[16];

    const int tid = threadIdx.x;
    const int bb = blockIdx.x >> 8;
    const int chunk = blockIdx.x & 255;
    const int n0 = chunk * 16;
    float* base = io + (size_t)bb * CDIM * NTOK + n0;

    #pragma unroll
    for (int i = 0; i < 8; ++i) {
        const int idx = tid + i * 256;
        const int c = idx >> 2;
        const int f4 = (idx & 3) * 4;
        const float4 vx = *(const float4*)(base + (size_t)c * NTOK + f4);
        xs[c][f4 + 0] = vx.x; xs[c][f4 + 1] = vx.y;
        xs[c][f4 + 2] = vx.z; xs[c][f4 + 3] = vx.w;
    }
    __syncthreads();

    const int n = tid >> 4;
    const int p = tid & 15;
    float s = 0.f;
    #pragma unroll 8
    for (int ci = 0; ci < 32; ++ci) {
        const int c = p * 32 + ((ci + 2 * p) & 31);
        s += xs[c][n];
    }
    s += __shfl_xor(s, 1, 64);
    s += __shfl_xor(s, 2, 64);
    s += __shfl_xor(s, 4, 64);
    s += __shfl_xor(s, 8, 64);
    if (p == 0) mu_s[n] = s * (1.f / 512.f);
    __syncthreads();
    const float mu = mu_s[n];
    float s2 = 0.f;
    #pragma unroll 8
    for (int ci = 0; ci < 32; ++ci) {
        const int c = p * 32 + ((ci + 2 * p) & 31);
        const float x = xs[c][n] - mu;
        s2 = fmaf(x, x, s2);
    }
    s2 += __shfl_xor(s2, 1, 64);
    s2 += __shfl_xor(s2, 2, 64);
    s2 += __shfl_xor(s2, 4, 64);
    s2 += __shfl_xor(s2, 8, 64);
    if (p == 0) rs_s[n] = rsqrtf(s2 * (1.f / 512.f) + EPS_LN);
    __syncthreads();

    #pragma unroll
    for (int i = 0; i < 8; ++i) {
        const int idx = tid + i * 256;
        const int c = idx >> 2;
        const int f4 = (idx & 3) * 4;
        const float w = ln_w[c];
        const float b2 = ln_b[c];
        float4 ov;
        ov.x = (xs[c][f4 + 0] - mu_s[f4 + 0]) * rs_s[f4 + 0] * w + b2;
        ov.y = (xs[c][f4 + 1] - mu_s[f4 + 1]) * rs_s[f4 + 1] * w + b2;
        ov.z = (xs[c][f4 + 2] - mu_s[f4 + 2]) * rs_s[f4 + 2] * w + b2;
        ov.w = (xs[c][f4 + 3] - mu_s[f4 + 3]) * rs_s[f4 + 3] * w + b2;
        *(float4*)(base + (size_t)c * NTOK + f4) = ov;
    }
}

// ---------------------------------------------------------------------------
extern "C" void kernel_launch(void* const* d_in, const int* in_sizes, int n_in,
                              void* d_out, int out_size, void* d_ws, size_t ws_size,
                              hipStream_t stream) {
    (void)in_sizes; (void)n_in; (void)out_size; (void)ws_size;
    const float* q    = (const float*)d_in[0];
    const float* k    = (const float*)d_in[1];
    const float* v    = (const float*)d_in[2];
    const float* fm_w = (const float*)d_in[3];
    const float* fm_b = (const float*)d_in[4];
    const float* ln_w = (const float*)d_in[5];
    const float* ln_b = (const float*)d_in[6];
    float* out = (float*)d_out;

    // ws layout (all regions fully written before read; no memset needed):
    float* kf_ws   = (float*)d_ws;                                   // 64*64*4096
    float* kv_part = kf_ws   + (size_t)NPAIRS * HD * NTOK;           // 16*64*64*64
    float* ks_part = kv_part + (size_t)KV_SPLIT * NPAIRS * HD * HD;  // 64*64*64
    float* kv_g    = ks_part + (size_t)64 * NPAIRS * HD;             // 64*4096
    float* ksum_g  = kv_g    + (size_t)NPAIRS * HD * HD;             // 64*64

    k_feat_k<<<NPAIRS * 64, 256, 0, stream>>>(k, fm_w, fm_b, kf_ws, ks_part);
    k_kv<<<NPAIRS * KV_SPLIT, 256, 0, stream>>>(v, kf_ws, kv_part);
    k_reduce<<<NPAIRS * 4, 256, 0, stream>>>(kv_part, ks_part, kv_g, ksum_g);
    k_qout<<<NPAIRS * (NTOK / 64), 256, 0, stream>>>(q, fm_w, fm_b, kv_g, ksum_g, out);
    k_layernorm<<<8 * (NTOK / 16), 256, 0, stream>>>(out, ln_w, ln_b);
}